// Round 3
// baseline (312.263 us; speedup 1.0000x reference)
//
#include <hip/hip_runtime.h>
#include <hip/hip_bf16.h>

// Problem: Tokenizer. x: (16, 3, 1024, 1024) f32. Output: (16, 512) int32.
// Pipeline: patch means -> direction argmin -> closed-form 4x fold -> per-batch argmax center
//           -> rank by (-distance, pos) -> quantize/pack base-8 -> keep 128 per level.
//
// Key algebraic collapse: in _fold, `add` depends only on `direction` (never changes) and
// valid==1 always, so after 4 folds: one_hot = onehot0 + add*(1+s+s^2+s^3), scope = s^4,
// with s = 1 + (# of 8-neighbors sharing this patch's direction). Integer-exact.

// ---------------- K1: per-patch direction ----------------
// One wave (64 lanes) per patch; block = 256 = 4 patches.
// Each lane: 4 consecutive elems of the 16x16 patch, 3 channels, float4 loads.
// Metric accumulation in double: exact sum of the exact-f32 |diff| terms -> best match
// to the numpy reference regardless of its summation order.
__global__ __launch_bounds__(256) void k_dir(const float* __restrict__ x,
                                             int* __restrict__ dir) {
    int t = threadIdx.x;
    int wave = t >> 6, lane = t & 63;
    int P = blockIdx.x * 4 + wave;          // global patch id
    int b = P >> 12, pid = P & 4095;
    int ph = pid >> 6, pw = pid & 63;
    int i = lane >> 2, j0 = (lane & 3) << 2;

    const float* base = x + (size_t)b * 3145728 + (size_t)(ph * 16 + i) * 1024 + pw * 16 + j0;
    float4 a0 = *(const float4*)(base);
    float4 a1 = *(const float4*)(base + 1048576);
    float4 a2 = *(const float4*)(base + 2097152);

    __shared__ float pl[4][16][17];          // +1 pad: conflict-free transposed reads
    float* row = &pl[wave][i][j0];
    // mean over channels in f32, matching ref op order: ((c0+c1)+c2)/3
    row[0] = (a0.x + a1.x + a2.x) / 3.0f;
    row[1] = (a0.y + a1.y + a2.y) / 3.0f;
    row[2] = (a0.z + a1.z + a2.z) / 3.0f;
    row[3] = (a0.w + a1.w + a2.w) / 3.0f;
    __syncthreads();

    const float (*p)[17] = pl[wave];
    double c0 = 0.0, c1 = 0.0, c2 = 0.0, c3 = 0.0;
#pragma unroll
    for (int q = 0; q < 4; ++q) {
        int j = j0 + q;
        float pij = p[i][j];
        if (j > i) {
            c0 += (double)fabsf(pij - p[j][i]);                // main-diagonal asymmetry
            c1 += (double)fabsf(p[15 - j][i] - p[15 - i][j]);  // anti-diagonal asymmetry
        }
        if (j < 8) c2 += (double)fabsf(pij - p[i][j + 8]);     // left vs right half
        if (i < 8) c3 += (double)fabsf(pij - p[i + 8][j]);     // top vs bottom half
    }
#pragma unroll
    for (int off = 32; off > 0; off >>= 1) {
        c0 += __shfl_xor(c0, off, 64);
        c1 += __shfl_xor(c1, off, 64);
        c2 += __shfl_xor(c2, off, 64);
        c3 += __shfl_xor(c3, off, 64);
    }
    if (lane == 0) {
        double d0 = c0 / 120.0;   // sq_tri = (256-16)/2
        double d1 = c1 / 120.0;
        double d2 = c2 / 128.0;   // sq = 256/2
        double d3 = c3 / 128.0;
        int dm = 0; double best = d0;                 // argmin, first-index tie-break
        if (d1 < best) { best = d1; dm = 1; }
        if (d2 < best) { best = d2; dm = 2; }
        if (d3 < best) { best = d3; dm = 3; }
        dir[P] = dm;
    }
}

// ---------------- K2: closed-form 4x fold ----------------
// one_hot_4[c] = onehot0[c] + add[c]*S, S = 1+s+s^2+s^3, s = 1+A (A = equal 8-neighbors).
// scope = s^4. All integer-exact (max one_hot = 1+2*820 = 1641, scope <= 6561).
__global__ __launch_bounds__(256) void k_fold(const int* __restrict__ dir,
                                              int* __restrict__ oh,
                                              int* __restrict__ scope) {
    int P = blockIdx.x * 256 + threadIdx.x;
    int b = P >> 12, pid = P & 4095;
    int h = pid >> 6, w = pid & 63;
    const int* db = dir + b * 4096;
    int d = db[pid];

    auto get = [&](int hh, int ww) -> int {
        if (hh < 0 || hh > 63 || ww < 0 || ww > 63) return 4;  // pad value
        return db[hh * 64 + ww];
    };
    int e_ul = (get(h - 1, w - 1) == d), e_u  = (get(h - 1, w) == d), e_ur = (get(h - 1, w + 1) == d);
    int e_l  = (get(h,     w - 1) == d),                              e_r  = (get(h,     w + 1) == d);
    int e_dl = (get(h + 1, w - 1) == d), e_dn = (get(h + 1, w) == d), e_dr = (get(h + 1, w + 1) == d);

    int add0 = e_ur + e_dl;   // channel 0: up-right + down-left
    int add1 = e_ul + e_dr;   // channel 1: up-left + down-right
    int add2 = e_u  + e_dn;   // channel 2: vertical
    int add3 = e_l  + e_r;    // channel 3: horizontal
    int A = add0 + add1 + add2 + add3;
    int s = 1 + A;
    int s2 = s * s;
    int S = 1 + s + s2 + s2 * s;

    oh[P * 4 + 0] = (d == 0) + add0 * S;
    oh[P * 4 + 1] = (d == 1) + add1 * S;
    oh[P * 4 + 2] = (d == 2) + add2 * S;
    oh[P * 4 + 3] = (d == 3) + add3 * S;
    scope[P] = s2 * s2;
}

// ---------------- K3: per-batch argmax of scope (first occurrence) ----------------
__global__ __launch_bounds__(256) void k_center(const int* __restrict__ scope,
                                                int* __restrict__ center) {
    int b = blockIdx.x;
    int t = threadIdx.x;
    const int* sb = scope + b * 4096;
    int bv = -1, bi = 0;
    for (int k = t; k < 4096; k += 256) {       // ascending k: '>' keeps first max
        int v = sb[k];
        if (v > bv) { bv = v; bi = k; }
    }
#pragma unroll
    for (int off = 32; off > 0; off >>= 1) {
        int ov = __shfl_xor(bv, off, 64);
        int oi = __shfl_xor(bi, off, 64);
        if (ov > bv || (ov == bv && oi < bi)) { bv = ov; bi = oi; }
    }
    __shared__ int sv[4], si[4];
    int wave = t >> 6, lane = t & 63;
    if (lane == 0) { sv[wave] = bv; si[wave] = bi; }
    __syncthreads();
    if (t == 0) {
        for (int wv = 1; wv < 4; ++wv)
            if (sv[wv] > bv || (sv[wv] == bv && si[wv] < bi)) { bv = sv[wv]; bi = si[wv]; }
        center[b] = bi;
    }
}

// ---------------- K4: rank by (-distance, pos), quantize, pack, scatter ----------------
// key = ((8191-d) << 12) | pos  (d <= 7938); ascending-key rank == stable argsort(-distance).
// Needed ranks: [0,128) in each of the 4 levels of 1024 -> out col = level*128 + (rank%1024).
__global__ __launch_bounds__(256) void k_token(const int* __restrict__ oh,
                                               const int* __restrict__ center,
                                               int* __restrict__ out) {
    int b = blockIdx.x >> 4;        // 16 slices per batch
    int slice = blockIdx.x & 15;
    int t = threadIdx.x;
    int idx = center[b];
    int ch = idx >> 6, cw = idx & 63;

    __shared__ int keys[4096];
#pragma unroll
    for (int q = 0; q < 16; ++q) {
        int j = q * 256 + t;        // coalesced, conflict-free LDS fill
        int h = j >> 6, w = j & 63;
        int dh = ch - h, dw = cw - w;
        int d = dh * dh + dw * dw;
        keys[j] = ((8191 - d) << 12) | j;
    }
    __syncthreads();

    int k = slice * 256 + t;        // my patch within batch
    int h = k >> 6, w = k & 63;
    int dh = ch - h, dw = cw - w;
    int d = dh * dh + dw * dw;
    int mykey = ((8191 - d) << 12) | k;

    int rank = 0;
    const int4* k4 = (const int4*)keys;   // broadcast b128 reads
    for (int j = 0; j < 1024; ++j) {
        int4 v = k4[j];
        rank += (v.x < mykey) + (v.y < mykey) + (v.z < mykey) + (v.w < mykey);
    }

    int level = rank >> 10, pil = rank & 1023;
    if (pil < 128) {
        int P = b * 4096 + k;
        int o0 = oh[P * 4 + 0], o1 = oh[P * 4 + 1], o2 = oh[P * 4 + 2], o3 = oh[P * 4 + 3];
        float sum = (float)(o0 + o1 + o2 + o3);     // exact: ints << 2^24
        // exactly (oh/sum)*8, round-half-even, clamp at 8 — matches jnp.round semantics
        float t0 = fminf(rintf(((float)o0 / sum) * 8.0f), 8.0f);
        float t1 = fminf(rintf(((float)o1 / sum) * 8.0f), 8.0f);
        float t2 = fminf(rintf(((float)o2 / sum) * 8.0f), 8.0f);
        float t3 = fminf(rintf(((float)o3 / sum) * 8.0f), 8.0f);
        float tok = 512.0f * t0 + 64.0f * t1 + 8.0f * t2 + t3;   // exact integer in f32
        out[b * 512 + (level << 7) + pil] = (int)tok;            // OUTPUT IS INT32
    }
}

extern "C" void kernel_launch(void* const* d_in, const int* in_sizes, int n_in,
                              void* d_out, int out_size, void* d_ws, size_t ws_size,
                              hipStream_t stream) {
    const float* x = (const float*)d_in[0];
    int* out = (int*)d_out;   // reference output dtype is int32

    char* ws = (char*)d_ws;
    int* dir    = (int*)(ws);                                    // 256 KB
    int* oh     = (int*)(ws + (256 << 10));                      // 1 MB
    int* scope  = (int*)(ws + (256 << 10) + (1 << 20));          // 256 KB
    int* center = (int*)(ws + (256 << 10) + (1 << 20) + (256 << 10)); // 64 B

    k_dir   <<<16384, 256, 0, stream>>>(x, dir);
    k_fold  <<<256,   256, 0, stream>>>(dir, oh, scope);
    k_center<<<16,    256, 0, stream>>>(scope, center);
    k_token <<<256,   256, 0, stream>>>(oh, center, out);
}

// Round 4
// 300.955 us; speedup vs baseline: 1.0376x; 1.0376x over previous
//
#include <hip/hip_runtime.h>
#include <hip/hip_bf16.h>

// Problem: Tokenizer. x: (16, 3, 1024, 1024) f32. Output: (16, 512) int32.
// Pipeline: patch means -> direction argmin -> closed-form 4x fold (+ fused argmax center)
//           -> rank by (-distance, pos) -> quantize/pack base-8 -> keep 128 per level.
//
// Fold collapse: add[] depends only on direction (constant across folds), valid==1, so
// one_hot = onehot0 + add*(1+s+s^2+s^3), scope = s^4, s = 1 + (#equal 8-neighbors).

// ---------------- K1: per-patch direction ----------------
// One wave per patch; block = 4 patches. float4 loads, LDS 16x17 tile, f64-exact metric sums.
__global__ __launch_bounds__(256) void k_dir(const float* __restrict__ x,
                                             int* __restrict__ dir,
                                             int* __restrict__ centerkey) {
    int t = threadIdx.x;
    if (blockIdx.x == 0 && t < 16) centerkey[t] = -1;   // init for K2's atomicMax (ws is poisoned)
    int wave = t >> 6, lane = t & 63;
    int P = blockIdx.x * 4 + wave;          // global patch id
    int b = P >> 12, pid = P & 4095;
    int ph = pid >> 6, pw = pid & 63;
    int i = lane >> 2, j0 = (lane & 3) << 2;

    const float* base = x + (size_t)b * 3145728 + (size_t)(ph * 16 + i) * 1024 + pw * 16 + j0;
    float4 a0 = *(const float4*)(base);
    float4 a1 = *(const float4*)(base + 1048576);
    float4 a2 = *(const float4*)(base + 2097152);

    __shared__ float pl[4][16][17];          // +1 pad: conflict-free transposed reads
    float* row = &pl[wave][i][j0];
    row[0] = (a0.x + a1.x + a2.x) / 3.0f;    // channel mean, ref op order
    row[1] = (a0.y + a1.y + a2.y) / 3.0f;
    row[2] = (a0.z + a1.z + a2.z) / 3.0f;
    row[3] = (a0.w + a1.w + a2.w) / 3.0f;
    __syncthreads();

    const float (*p)[17] = pl[wave];
    double c0 = 0.0, c1 = 0.0, c2 = 0.0, c3 = 0.0;   // exact sum of exact-f32 terms
#pragma unroll
    for (int q = 0; q < 4; ++q) {
        int j = j0 + q;
        float pij = p[i][j];
        if (j > i) {
            c0 += (double)fabsf(pij - p[j][i]);                // main-diag asymmetry
            c1 += (double)fabsf(p[15 - j][i] - p[15 - i][j]);  // anti-diag asymmetry
        }
        if (j < 8) c2 += (double)fabsf(pij - p[i][j + 8]);     // left|right half
        if (i < 8) c3 += (double)fabsf(pij - p[i + 8][j]);     // top|bottom half
    }
#pragma unroll
    for (int off = 32; off > 0; off >>= 1) {
        c0 += __shfl_xor(c0, off, 64);
        c1 += __shfl_xor(c1, off, 64);
        c2 += __shfl_xor(c2, off, 64);
        c3 += __shfl_xor(c3, off, 64);
    }
    if (lane == 0) {
        double d0 = c0 / 120.0;   // sq_tri
        double d1 = c1 / 120.0;
        double d2 = c2 / 128.0;   // sq
        double d3 = c3 / 128.0;
        int dm = 0; double best = d0;                 // argmin, first-index tie-break
        if (d1 < best) { best = d1; dm = 1; }
        if (d2 < best) { best = d2; dm = 2; }
        if (d3 < best) { best = d3; dm = 3; }
        dir[P] = dm;
    }
}

// ---------------- K2: closed-form fold + fused per-batch center argmax ----------------
// key = (scope<<12) | (4095-pid): atomicMax == first-occurrence argmax of scope (scope<=6561).
__global__ __launch_bounds__(256) void k_foldcenter(const int* __restrict__ dir,
                                                    int* __restrict__ oh,
                                                    int* __restrict__ centerkey) {
    int P = blockIdx.x * 256 + threadIdx.x;
    int b = P >> 12, pid = P & 4095;
    int h = pid >> 6, w = pid & 63;
    const int* db = dir + b * 4096;
    int d = db[pid];

    auto get = [&](int hh, int ww) -> int {
        if (hh < 0 || hh > 63 || ww < 0 || ww > 63) return 4;  // pad
        return db[hh * 64 + ww];
    };
    int add0 = (get(h - 1, w + 1) == d) + (get(h + 1, w - 1) == d);  // anti-diag neighbors
    int add1 = (get(h - 1, w - 1) == d) + (get(h + 1, w + 1) == d);  // main-diag neighbors
    int add2 = (get(h - 1, w) == d) + (get(h + 1, w) == d);          // vertical
    int add3 = (get(h, w - 1) == d) + (get(h, w + 1) == d);          // horizontal
    int s = 1 + add0 + add1 + add2 + add3;
    int s2 = s * s;
    int S = 1 + s + s2 + s2 * s;

    ((int4*)oh)[P] = make_int4((d == 0) + add0 * S, (d == 1) + add1 * S,
                               (d == 2) + add2 * S, (d == 3) + add3 * S);

    int key = (s2 * s2 << 12) | (4095 - pid);
#pragma unroll
    for (int off = 32; off > 0; off >>= 1)
        key = max(key, __shfl_xor(key, off, 64));
    __shared__ int wmax[4];
    if ((threadIdx.x & 63) == 0) wmax[threadIdx.x >> 6] = key;
    __syncthreads();
    if (threadIdx.x == 0)
        atomicMax(&centerkey[b], max(max(wmax[0], wmax[1]), max(wmax[2], wmax[3])));
}

// ---------------- K3: rank by (-distance, pos), quantize, pack, scatter ----------------
// rankkey = ((8191-d)<<12) | pos; ascending rank == stable argsort(-distance).
// Unroll-8 + 4 accumulators: keeps ~8 LDS reads in flight (no serial 120-cyc chain).
__global__ __launch_bounds__(256) void k_token(const int* __restrict__ oh,
                                               const int* __restrict__ centerkey,
                                               int* __restrict__ out) {
    int b = blockIdx.x >> 4;        // 16 slices per batch
    int slice = blockIdx.x & 15;
    int t = threadIdx.x;
    int idx = 4095 - (centerkey[b] & 4095);
    int ch = idx >> 6, cw = idx & 63;

    __shared__ int keys[4096];
#pragma unroll
    for (int q = 0; q < 16; ++q) {
        int j = q * 256 + t;
        int dh = ch - (j >> 6), dw = cw - (j & 63);
        keys[j] = ((8191 - (dh * dh + dw * dw)) << 12) | j;
    }
    __syncthreads();

    int k = slice * 256 + t;
    int dh = ch - (k >> 6), dw = cw - (k & 63);
    int mykey = ((8191 - (dh * dh + dw * dw)) << 12) | k;

    int r0 = 0, r1 = 0, r2 = 0, r3 = 0;
    const int4* k4 = (const int4*)keys;   // broadcast b128 reads
#pragma unroll 8
    for (int j = 0; j < 1024; ++j) {
        int4 v = k4[j];
        r0 += (v.x < mykey);
        r1 += (v.y < mykey);
        r2 += (v.z < mykey);
        r3 += (v.w < mykey);
    }
    int rank = (r0 + r1) + (r2 + r3);

    int level = rank >> 10, pil = rank & 1023;
    if (pil < 128) {
        int4 o = ((const int4*)oh)[b * 4096 + k];
        float sum = (float)(o.x + o.y + o.z + o.w);   // exact: ints << 2^24
        // exactly (oh/sum)*8, round-half-even (RNE is HW default) == jnp.round
        float t0 = fminf(rintf(((float)o.x / sum) * 8.0f), 8.0f);
        float t1 = fminf(rintf(((float)o.y / sum) * 8.0f), 8.0f);
        float t2 = fminf(rintf(((float)o.z / sum) * 8.0f), 8.0f);
        float t3 = fminf(rintf(((float)o.w / sum) * 8.0f), 8.0f);
        float tok = 512.0f * t0 + 64.0f * t1 + 8.0f * t2 + t3;   // exact integer in f32
        out[b * 512 + (level << 7) + pil] = (int)tok;            // int32 output
    }
}

extern "C" void kernel_launch(void* const* d_in, const int* in_sizes, int n_in,
                              void* d_out, int out_size, void* d_ws, size_t ws_size,
                              hipStream_t stream) {
    const float* x = (const float*)d_in[0];
    int* out = (int*)d_out;   // reference output dtype is int32

    char* ws = (char*)d_ws;
    int* dir       = (int*)(ws);                                 // 256 KB
    int* oh        = (int*)(ws + (256 << 10));                   // 1 MB
    int* centerkey = (int*)(ws + (256 << 10) + (1 << 20));       // 64 B

    k_dir       <<<16384, 256, 0, stream>>>(x, dir, centerkey);
    k_foldcenter<<<256,   256, 0, stream>>>(dir, oh, centerkey);
    k_token     <<<256,   256, 0, stream>>>(oh, centerkey, out);
}

// Round 6
// 293.696 us; speedup vs baseline: 1.0632x; 1.0247x over previous
//
#include <hip/hip_runtime.h>
#include <hip/hip_bf16.h>

// Problem: Tokenizer. x: (16, 3, 1024, 1024) f32. Output: (16, 512) int32.
// patch means -> direction argmin -> closed-form 4x fold + fused center argmax
// -> ANALYTIC rank by (-distance, pos) -> quantize/pack base-8 -> keep 128/level.
//
// Fold collapse: add[] depends only on direction (constant across folds), valid==1, so
// one_hot = onehot0 + add*(1+s+s^2+s^3), scope = s^4, s = 1 + (#equal 8-neighbors).
// Rank collapse: rank(p) = #{q: d_q > d_p} + #{q: d_q = d_p, pos_q < pos_p}; per lattice
// row this is an interval-complement count (integer isqrt) + <=2 boundary tie checks.

// ---------------- K1: per-patch direction ----------------
// Block = one 16-row x 256-col strip (16 patches). Each wave loads 4 image rows x 3
// channels as contiguous 1KB-per-instruction float4s, builds LDS mean[16][257], then
// computes 4 patches' metrics (f64-exact sums -> bit-stable argmin).
__global__ __launch_bounds__(256) void k_dir(const float* __restrict__ x,
                                             int* __restrict__ dir,
                                             int* __restrict__ centerkey) {
    int t = threadIdx.x;
    if (blockIdx.x == 0 && t < 16) centerkey[t] = -1;   // init for K2 atomicMax (ws poisoned)
    int wave = t >> 6, lane = t & 63;
    int b    = blockIdx.x >> 8;        // batch
    int rem  = blockIdx.x & 255;
    int ph   = rem >> 2;               // patch row 0..63
    int tile = rem & 3;                // 256-col tile (16 patches)

    __shared__ float mean[16][257];    // +1 pad: (row + col) % 32 banks -> conflict-free reads

    const float* bx = x + (size_t)b * 3145728 + (size_t)(ph * 16) * 1024 + tile * 256 + lane * 4;
#pragma unroll
    for (int rr = 0; rr < 4; ++rr) {
        int r = wave * 4 + rr;                       // this wave owns rows wave*4..+3
        const float* rp = bx + (size_t)r * 1024;
        float4 a0 = *(const float4*)(rp);            // 64 lanes x 16B = 1KB contiguous
        float4 a1 = *(const float4*)(rp + 1048576);
        float4 a2 = *(const float4*)(rp + 2097152);
        float* m = &mean[r][lane * 4];
        m[0] = (a0.x + a1.x + a2.x) / 3.0f;          // channel mean, ref op order
        m[1] = (a0.y + a1.y + a2.y) / 3.0f;
        m[2] = (a0.z + a1.z + a2.z) / 3.0f;
        m[3] = (a0.w + a1.w + a2.w) / 3.0f;
    }
    __syncthreads();

    int i = lane >> 2, j0 = (lane & 3) << 2;
#pragma unroll
    for (int pp = 0; pp < 4; ++pp) {
        int pat = wave * 4 + pp;                     // patch 0..15 within strip
        int cb = pat * 16;
        double c0 = 0.0, c1 = 0.0, c2 = 0.0, c3 = 0.0;   // exact sums of exact-f32 terms
#pragma unroll
        for (int q = 0; q < 4; ++q) {
            int j = j0 + q;
            float pij = mean[i][cb + j];
            if (j > i) {
                c0 += (double)fabsf(pij - mean[j][cb + i]);                  // main-diag
                c1 += (double)fabsf(mean[15 - j][cb + i] - mean[15 - i][cb + j]); // anti-diag
            }
            if (j < 8) c2 += (double)fabsf(pij - mean[i][cb + j + 8]);       // left|right
            if (i < 8) c3 += (double)fabsf(pij - mean[i + 8][cb + j]);       // top|bottom
        }
#pragma unroll
        for (int off = 32; off > 0; off >>= 1) {
            c0 += __shfl_xor(c0, off, 64);
            c1 += __shfl_xor(c1, off, 64);
            c2 += __shfl_xor(c2, off, 64);
            c3 += __shfl_xor(c3, off, 64);
        }
        if (lane == 0) {
            double d0 = c0 / 120.0;   // sq_tri
            double d1 = c1 / 120.0;
            double d2 = c2 / 128.0;   // sq
            double d3 = c3 / 128.0;
            int dm = 0; double best = d0;            // argmin, first-index tie-break
            if (d1 < best) { best = d1; dm = 1; }
            if (d2 < best) { best = d2; dm = 2; }
            if (d3 < best) { best = d3; dm = 3; }
            dir[b * 4096 + ph * 64 + tile * 16 + pat] = dm;
        }
    }
}

// ---------------- K2: closed-form fold + fused per-batch center argmax ----------------
// key = (scope<<12) | (4095-pid): atomicMax == first-occurrence argmax (scope<=6561).
__global__ __launch_bounds__(256) void k_foldcenter(const int* __restrict__ dir,
                                                    int* __restrict__ oh,
                                                    int* __restrict__ centerkey) {
    int P = blockIdx.x * 256 + threadIdx.x;
    int b = P >> 12, pid = P & 4095;
    int h = pid >> 6, w = pid & 63;
    const int* db = dir + b * 4096;
    int d = db[pid];

    auto get = [&](int hh, int ww) -> int {
        if (hh < 0 || hh > 63 || ww < 0 || ww > 63) return 4;  // pad
        return db[hh * 64 + ww];
    };
    int add0 = (get(h - 1, w + 1) == d) + (get(h + 1, w - 1) == d);  // anti-diag nbrs
    int add1 = (get(h - 1, w - 1) == d) + (get(h + 1, w + 1) == d);  // main-diag nbrs
    int add2 = (get(h - 1, w) == d) + (get(h + 1, w) == d);          // vertical
    int add3 = (get(h, w - 1) == d) + (get(h, w + 1) == d);          // horizontal
    int s = 1 + add0 + add1 + add2 + add3;
    int s2 = s * s;
    int S = 1 + s + s2 + s2 * s;

    ((int4*)oh)[P] = make_int4((d == 0) + add0 * S, (d == 1) + add1 * S,
                               (d == 2) + add2 * S, (d == 3) + add3 * S);

    int key = (s2 * s2 << 12) | (4095 - pid);
#pragma unroll
    for (int off = 32; off > 0; off >>= 1)
        key = max(key, __shfl_xor(key, off, 64));
    __shared__ int wmax[4];
    if ((threadIdx.x & 63) == 0) wmax[threadIdx.x >> 6] = key;
    __syncthreads();
    if (threadIdx.x == 0)
        atomicMax(&centerkey[b], max(max(wmax[0], wmax[1]), max(wmax[2], wmax[3])));
}

// ---------------- K3: analytic rank + quantize + pack + scatter ----------------
// rank = sum over rows h of (64 - |{w: (cw-w)^2 <= t}|), t = dp-(ch-h)^2, plus tie
// credits at the <=2 perfect-square boundary points with smaller pos. Pure VALU.
__global__ __launch_bounds__(256) void k_token(const int* __restrict__ oh,
                                               const int* __restrict__ centerkey,
                                               int* __restrict__ out) {
    int b = blockIdx.x >> 4;
    int k = (blockIdx.x & 15) * 256 + threadIdx.x;   // my pos in batch
    int idx = 4095 - (centerkey[b] & 4095);
    int ch = idx >> 6, cw = idx & 63;
    int hp = k >> 6, wp = k & 63;
    int dhp = ch - hp, dwp = cw - wp;
    int dp = dhp * dhp + dwp * dwp;

    int rank = 0;
#pragma unroll 4
    for (int h = 0; h < 64; ++h) {
        int dh = ch - h;
        int tt = dp - dh * dh;
        if (tt < 0) { rank += 64; continue; }        // whole row farther than me
        int s = (int)sqrtf((float)tt);               // exact isqrt with +-1 correction
        if (s * s > tt) --s;
        else if ((s + 1) * (s + 1) <= tt) ++s;
        int lo = max(0, cw - s), hi = min(63, cw + s);
        rank += 64 - (hi - lo + 1);                  // strictly-farther count in row
        if (s * s == tt) {                            // equal-distance boundary points
            int base = h << 6;
            int w1 = cw - s, w2 = cw + s;
            if (w1 >= 0 && w1 <= 63 && (base + w1) < k) ++rank;
            if (s > 0 && w2 >= 0 && w2 <= 63 && (base + w2) < k) ++rank;
        }
    }

    int level = rank >> 10, pil = rank & 1023;
    if (pil < 128) {
        int4 o = ((const int4*)oh)[b * 4096 + k];
        float sum = (float)(o.x + o.y + o.z + o.w);   // exact: ints << 2^24
        // exactly (oh/sum)*8, RNE rounding == jnp.round, clamp at 8
        float t0 = fminf(rintf(((float)o.x / sum) * 8.0f), 8.0f);
        float t1 = fminf(rintf(((float)o.y / sum) * 8.0f), 8.0f);
        float t2 = fminf(rintf(((float)o.z / sum) * 8.0f), 8.0f);
        float t3 = fminf(rintf(((float)o.w / sum) * 8.0f), 8.0f);
        float tok = 512.0f * t0 + 64.0f * t1 + 8.0f * t2 + t3;   // exact integer in f32
        out[b * 512 + (level << 7) + pil] = (int)tok;            // int32 output
    }
}

extern "C" void kernel_launch(void* const* d_in, const int* in_sizes, int n_in,
                              void* d_out, int out_size, void* d_ws, size_t ws_size,
                              hipStream_t stream) {
    const float* x = (const float*)d_in[0];
    int* out = (int*)d_out;   // reference output dtype is int32

    char* ws = (char*)d_ws;
    int* dir       = (int*)(ws);                                 // 256 KB
    int* oh        = (int*)(ws + (256 << 10));                   // 1 MB
    int* centerkey = (int*)(ws + (256 << 10) + (1 << 20));       // 64 B

    k_dir       <<<4096, 256, 0, stream>>>(x, dir, centerkey);
    k_foldcenter<<<256,  256, 0, stream>>>(dir, oh, centerkey);
    k_token     <<<256,  256, 0, stream>>>(oh, centerkey, out);
}